// Round 8
// baseline (139.216 us; speedup 1.0000x reference)
//
#include <hip/hip_runtime.h>
#include <math.h>

// MHAttention: BS=8, D=256, L=1024, H=8, DK=32
// Round 8: (1) attn XCD swizzle FIXED: bid = strip*64 + bh so XCD = bh%8 is
// strip-invariant -> each XCD's L2 holds only its 8 bh's K/V (1 MB) and HBM
// K/V fetch drops ~8x. (R7 comment had it backwards: strip in low bits
// spreads one bh's strips over all 8 XCDs.) (2) proj uses the matching
// swizzle. (3) outproj rewritten zero-LDS (A = val rows, B = Wp rows, both
// straight from global) -> no barrier, 4 blocks/CU x 4 waves.

constexpr int cD  = 256;
constexpr int cL  = 1024;
constexpr int cH  = 8;
constexpr int cDK = 32;

typedef _Float16 f16;
typedef __attribute__((ext_vector_type(8))) _Float16 h8;   // 8 f16 = 4 VGPRs
typedef __attribute__((ext_vector_type(4))) _Float16 h4;   // 8 B
typedef __attribute__((ext_vector_type(4))) float f4v;     // MFMA C/D

// ---------------------------------------------------------------------------
// Kernel 1: Q,K,V projections via MFMA, zero LDS. grid 1024 = lt*64 + bh;
// wave w owns l-subtile l0 + w*16 + ln15.
// D[c][l] = sum_j W[c][j] * X[j][l]  (A = W fp16 frag, B = X^T column frag)
// Outputs: qp[bh][r][c] (B-frag layout for attn), kp[bh][e][c] masked,
// vp[bh][c][e].
// ---------------------------------------------------------------------------
__global__ __launch_bounds__(256, 4) void proj_qkv_kernel(
    const float* __restrict__ queries, const float* __restrict__ keys,
    const float* __restrict__ values, const float* __restrict__ mask,
    const float* __restrict__ Wq, const float* __restrict__ Wk,
    const float* __restrict__ Wv, f16* __restrict__ qp_h,
    f16* __restrict__ kp_h, f16* __restrict__ vp_h)
{
    const int t    = threadIdx.x;
    const int bid  = blockIdx.x;
    const int bh   = bid & 63;             // XCD = bh%8, matches attn
    const int lt   = bid >> 6;
    const int h    = bh & 7;
    const int b    = bh >> 3;
    const int l0   = lt * 64;
    const int lane = t & 63, w = t >> 6, ln15 = lane & 15, lq = lane >> 4;
    const int l    = l0 + w * 16 + ln15;     // this lane's l (MFMA n-index)

    const float mk = mask[b * cL + l];
    const size_t xbase = ((size_t)(b * cD + h * cDK)) * cL + l;   // + j*cL
    const int    wbase = h * cDK * cDK + lq * 8;                  // + c*cDK

    const float* Xs[3] = {queries, keys, values};
    const float* Ws[3] = {Wq, Wk, Wv};
    f4v d0[3], d1[3];

    #pragma unroll
    for (int m = 0; m < 3; ++m) {
        const float* __restrict__ X = Xs[m];
        const float* __restrict__ W = Ws[m];
        h8 bx, a0, a1;
        #pragma unroll
        for (int i = 0; i < 8; ++i)
            bx[i] = (f16)X[xbase + (size_t)(lq * 8 + i) * cL];
        #pragma unroll
        for (int i = 0; i < 8; ++i) {
            a0[i] = (f16)W[wbase + ln15 * cDK + i];
            a1[i] = (f16)W[wbase + (16 + ln15) * cDK + i];
        }
        f4v z = {0.f, 0.f, 0.f, 0.f};
        d0[m] = __builtin_amdgcn_mfma_f32_16x16x32_f16(a0, bx, z, 0, 0, 0);
        d1[m] = __builtin_amdgcn_mfma_f32_16x16x32_f16(a1, bx, z, 0, 0, 0);
    }

    // ---- Q: [r=l][c], fp16 ----
    {
        const size_t qb = ((size_t)bh * cL + l) * cDK;
        h4 o0, o1;
        #pragma unroll
        for (int i = 0; i < 4; ++i) { o0[i] = (f16)d0[0][i]; o1[i] = (f16)d1[0][i]; }
        *reinterpret_cast<h4*>(&qp_h[qb + lq * 4])      = o0;
        *reinterpret_cast<h4*>(&qp_h[qb + 16 + lq * 4]) = o1;
    }
    // ---- K: [e=l][c], masked ----
    {
        const size_t kb = ((size_t)bh * cL + l) * cDK;
        h4 o0, o1;
        #pragma unroll
        for (int i = 0; i < 4; ++i) {
            o0[i] = (f16)(d0[1][i] * mk);
            o1[i] = (f16)(d1[1][i] * mk);
        }
        *reinterpret_cast<h4*>(&kp_h[kb + lq * 4])      = o0;
        *reinterpret_cast<h4*>(&kp_h[kb + 16 + lq * 4]) = o1;
    }
    // ---- V: [c][e=l] ----
    {
        const size_t vb = (size_t)bh * cDK * cL + l;
        #pragma unroll
        for (int i = 0; i < 4; ++i) {
            vp_h[vb + (size_t)(lq * 4 + i) * cL]      = (f16)d0[2][i];
            vp_h[vb + (size_t)(16 + lq * 4 + i) * cL] = (f16)d1[2][i];
        }
    }
}

// ---------------------------------------------------------------------------
// Kernel 2: fused attention, fp16 MFMA. Block = (b, h, 64-row strip), 4
// waves; wave w owns rows r = w*16 + ln15 (one row per lane end-to-end).
// grid 1024 = strip*64 + bh: XCD = bh%8 for every strip -> each XCD's L2
// serves its 8 bh's K/V (1 MB) for all 16 strips. 28 KB LDS -> 5 blocks/CU.
// ---------------------------------------------------------------------------
__global__ __launch_bounds__(256, 5) void attn_kernel(
    const float* __restrict__ mask, const f16* __restrict__ qp_h,
    const f16* __restrict__ kp_h, const f16* __restrict__ vp_h,
    f16* __restrict__ val_h)
{
    __shared__ __align__(16) char smem[28672];
    f16* ks  = (f16*)smem;             // [2][64e][40]  10240 B, rows 80 B
    f16* vsb = (f16*)(smem + 10240);   // [2][32c][72]   9216 B, rows 144 B
    f16* pbf = (f16*)(smem + 19456);   // [64r][72]      9216 B, rows 144 B

    const int t     = threadIdx.x;
    const int bid   = blockIdx.x;
    const int bh    = bid & 63;        // XCD = bh%8: strip-invariant
    const int strip = bid >> 6;
    const int b     = bh >> 3;
    const int r0    = strip * 64;
    const int lane  = t & 63;
    const int w     = t >> 6;
    const int ln15  = lane & 15;
    const int lq    = lane >> 4;

    const size_t kvbase = ((size_t)bh) * 32768;             // f16 units
    const int se = t >> 2, sb = (t & 3) * 8;                // K staging coords
    const int vc = t >> 3, veb = (t & 7) * 8;               // V staging coords

    // ---- persistent B-frag: this lane's q row, straight from global ----
    const h8 qf = *reinterpret_cast<const h8*>(
        &qp_h[((size_t)bh * cL + r0 + w * 16 + ln15) * cDK + lq * 8]);

    // ---- stage tile 0 into buf 0 ----
    {
        h8 kh = *reinterpret_cast<const h8*>(&kp_h[kvbase + se * 32 + sb]);
        *reinterpret_cast<h8*>(&ks[se * 40 + sb]) = kh;
        h8 vv = *reinterpret_cast<const h8*>(&vp_h[kvbase + vc * 1024 + veb]);
        *reinterpret_cast<h8*>(&vsb[vc * 72 + veb]) = vv;
    }

    f4v o0 = {0.f, 0.f, 0.f, 0.f}, o1 = {0.f, 0.f, 0.f, 0.f};
    float mo = -INFINITY, lrp = 0.f;   // lrp: per-lane partial (16 e-cols)
    const int prow  = (w * 16 + ln15) * 72;
    const int vsoff = ln15 * 72 + lq * 8;

    for (int et = 0; et < 16; ++et) {
        __syncthreads();        // tile et visible in buf pp
        const int pp = et & 1;
        const bool pre = (et < 15);
        h8 khp, vvp;
        if (pre) {              // early global loads for tile et+1
            const int e0n = (et + 1) * 64;
            khp = *reinterpret_cast<const h8*>(&kp_h[kvbase + (e0n + se) * 32 + sb]);
            vvp = *reinterpret_cast<const h8*>(&vp_h[kvbase + vc * 1024 + e0n + veb]);
        }
        // mask for this tile: broadcast global reads (L1-hot), prefetched
        float4 mk4[4];
        #pragma unroll
        for (int es = 0; es < 4; ++es)
            mk4[es] = *reinterpret_cast<const float4*>(
                &mask[b * cL + et * 64 + es * 16 + lq * 4]);

        // ---- S^T tiles: D[e][r] = K[e][c] x Q^T[c][r] ----
        f4v sA[4];
        #pragma unroll
        for (int es = 0; es < 4; ++es) {
            const h8 kf = *reinterpret_cast<const h8*>(
                &ks[pp * 2560 + (es * 16 + ln15) * 40 + lq * 8]);
            f4v z = {0.f, 0.f, 0.f, 0.f};
            sA[es] = __builtin_amdgcn_mfma_f32_16x16x32_f16(kf, qf, z, 0, 0, 0);
        }

        // ---- softmax: lane owns row r = w*16+ln15 (scalar stats) ----
        float tm = fmaxf(fmaxf(fmaxf(sA[0][0], sA[0][1]), fmaxf(sA[0][2], sA[0][3])),
                   fmaxf(fmaxf(fmaxf(sA[1][0], sA[1][1]), fmaxf(sA[1][2], sA[1][3])),
                   fmaxf(fmaxf(fmaxf(sA[2][0], sA[2][1]), fmaxf(sA[2][2], sA[2][3])),
                         fmaxf(fmaxf(sA[3][0], sA[3][1]), fmaxf(sA[3][2], sA[3][3])))));
        tm = fmaxf(tm, __shfl_xor(tm, 16));
        tm = fmaxf(tm, __shfl_xor(tm, 32));
        const float mn = fmaxf(mo, tm);
        const float al = __expf(mo - mn);     // first tile: exp(-inf) = 0
        mo = mn;
        o0[0] *= al; o0[1] *= al; o0[2] *= al; o0[3] *= al;
        o1[0] *= al; o1[1] *= al; o1[2] *= al; o1[3] *= al;

        float ps = 0.f;
        #pragma unroll
        for (int es = 0; es < 4; ++es) {
            // p = mask * exp(s - mn): inner mask-mul redundant (masked s=0<=mn)
            float p0 = mk4[es].x * __expf(sA[es][0] - mn);
            float p1 = mk4[es].y * __expf(sA[es][1] - mn);
            float p2 = mk4[es].z * __expf(sA[es][2] - mn);
            float p3 = mk4[es].w * __expf(sA[es][3] - mn);
            ps += (p0 + p1) + (p2 + p3);
            h4 pk; pk[0] = (f16)p0; pk[1] = (f16)p1; pk[2] = (f16)p2; pk[3] = (f16)p3;
            *reinterpret_cast<h4*>(&pbf[prow + es * 16 + lq * 4]) = pk;  // wave-private
        }
        lrp = lrp * al + ps;   // shuffle-reduce deferred to epilogue

        // ---- PV: o^T[c][r] += V[c][e] x P^T[e][r] (same-wave, no barrier) ----
        #pragma unroll
        for (int ch = 0; ch < 2; ++ch) {
            h8 pf  = *reinterpret_cast<const h8*>(&pbf[prow + ch * 32 + lq * 8]);
            h8 va0 = *reinterpret_cast<const h8*>(&vsb[pp * 2304 + vsoff + ch * 32]);
            h8 va1 = *reinterpret_cast<const h8*>(&vsb[pp * 2304 + vsoff + ch * 32 + 1152]);
            o0 = __builtin_amdgcn_mfma_f32_16x16x32_f16(va0, pf, o0, 0, 0, 0);
            o1 = __builtin_amdgcn_mfma_f32_16x16x32_f16(va1, pf, o1, 0, 0, 0);
        }

        // ---- late LDS writes: publish tile et+1 into buf pp^1 ----
        if (pre) {
            *reinterpret_cast<h8*>(&ks[(pp ^ 1) * 2560 + se * 40 + sb]) = khp;
            *reinterpret_cast<h8*>(&vsb[(pp ^ 1) * 2304 + vc * 72 + veb]) = vvp;
        }
    }

    // ---- epilogue: complete row-sum, divide, store ----
    {
        float lr = lrp;
        lr += __shfl_xor(lr, 16);
        lr += __shfl_xor(lr, 32);
        const float linv = 1.0f / (lr + 1e-8f);
        const int h = bh & 7;
        const size_t obase = ((size_t)(b * cL + r0 + w * 16 + ln15)) * cD + h * cDK;
        h4 q0, q1;
        #pragma unroll
        for (int i = 0; i < 4; ++i) {
            q0[i] = (f16)(o0[i] * linv);
            q1[i] = (f16)(o1[i] * linv);
        }
        *reinterpret_cast<h4*>(&val_h[obase + lq * 4])      = q0;
        *reinterpret_cast<h4*>(&val_h[obase + 16 + lq * 4]) = q1;
    }
}

// ---------------------------------------------------------------------------
// Kernel 3: out[b][l][i] = mask[b][l] * (sum_j Wp[i][j]*val[b][l][j] + bp[i])
// Zero-LDS fp16 MFMA: A-frag = val rows (h8 global), B-frag = Wp rows
// (2x float4 + cvt). D col = i = ln15 -> 4x64B-segment coalesced stores.
// grid 1024 = (b:8, lt:64 of 16 l, ih:2 of 128 i), block 256, no barrier.
// ---------------------------------------------------------------------------
__global__ __launch_bounds__(256, 4) void outproj_kernel(
    const f16* __restrict__ val_h, const float* __restrict__ Wp,
    const float* __restrict__ bp, const float* __restrict__ mask,
    float* __restrict__ out)
{
    const int t    = threadIdx.x;
    const int bid  = blockIdx.x;
    const int ih   = bid & 1;
    const int lt   = (bid >> 1) & 63;
    const int b    = bid >> 7;
    const int l0   = lt * 16;
    const int lane = t & 63, w = t >> 6, ln15 = lane & 15, lq = lane >> 4;
    const int i0   = ih * 128 + w * 32;    // wave covers 32 i (2 n-tiles)

    // ---- A-frags: val rows, straight from global (lane m=ln15 -> l) ----
    h8 af[8];
    const f16* vrow = &val_h[((size_t)(b * cL + l0 + ln15)) * cD + lq * 8];
    #pragma unroll
    for (int kc = 0; kc < 8; ++kc)
        af[kc] = *reinterpret_cast<const h8*>(vrow + kc * 32);

    const float4 mk4 = *reinterpret_cast<const float4*>(&mask[b * cL + l0 + lq * 4]);
    const float mks[4] = {mk4.x, mk4.y, mk4.z, mk4.w};

    #pragma unroll
    for (int nt = 0; nt < 2; ++nt) {
        const int i = i0 + nt * 16 + ln15;           // B-frag n-index
        const float* wrow = &Wp[(size_t)i * cD + lq * 8];
        f4v acc = {0.f, 0.f, 0.f, 0.f};
        #pragma unroll
        for (int kc = 0; kc < 8; ++kc) {
            float4 f0 = *reinterpret_cast<const float4*>(wrow + kc * 32);
            float4 f1 = *reinterpret_cast<const float4*>(wrow + kc * 32 + 4);
            h8 bf;
            bf[0] = (f16)f0.x; bf[1] = (f16)f0.y; bf[2] = (f16)f0.z; bf[3] = (f16)f0.w;
            bf[4] = (f16)f1.x; bf[5] = (f16)f1.y; bf[6] = (f16)f1.z; bf[7] = (f16)f1.w;
            acc = __builtin_amdgcn_mfma_f32_16x16x32_f16(af[kc], bf, acc, 0, 0, 0);
        }
        const float bpv = bp[i];
        #pragma unroll
        for (int reg = 0; reg < 4; ++reg) {          // D row m = lq*4+reg -> l
            const int l = l0 + lq * 4 + reg;
            out[((size_t)(b * cL + l)) * cD + i] = (acc[reg] + bpv) * mks[reg];
        }
    }
}

// ---------------------------------------------------------------------------
extern "C" void kernel_launch(void* const* d_in, const int* in_sizes, int n_in,
                              void* d_out, int out_size, void* d_ws, size_t ws_size,
                              hipStream_t stream) {
    const float* queries = (const float*)d_in[0];
    const float* keys    = (const float*)d_in[1];
    const float* values  = (const float*)d_in[2];
    const float* mask    = (const float*)d_in[3];
    const float* Wq      = (const float*)d_in[4];
    const float* Wk      = (const float*)d_in[5];
    const float* Wv      = (const float*)d_in[6];
    const float* Wp      = (const float*)d_in[7];
    const float* bp      = (const float*)d_in[8];
    float* out = (float*)d_out;

    // ws: qp 4MB | kp 4MB | vp 4MB | val 4MB  (16 MB)
    char* wsb = (char*)d_ws;
    f16* qp_h  = (f16*)(wsb);
    f16* kp_h  = (f16*)(wsb + (4u << 20));
    f16* vp_h  = (f16*)(wsb + (8u << 20));
    f16* val_h = (f16*)(wsb + (12u << 20));

    proj_qkv_kernel<<<dim3(1024), dim3(256), 0, stream>>>(
        queries, keys, values, mask, Wq, Wk, Wv, qp_h, kp_h, vp_h);
    attn_kernel<<<dim3(1024), dim3(256), 0, stream>>>(
        mask, qp_h, kp_h, vp_h, val_h);
    outproj_kernel<<<dim3(1024), dim3(256), 0, stream>>>(val_h, Wp, bp, mask, out);
}

// Round 9
// 128.653 us; speedup vs baseline: 1.0821x; 1.0821x over previous
//
#include <hip/hip_runtime.h>
#include <math.h>

// MHAttention: BS=8, D=256, L=1024, H=8, DK=32
// Round 9 = Round 8 proj/attn (XCD swizzle: bid low bits = bh, so XCD=bh%8
// is strip-invariant and each XCD's L2 holds only its 8 bh's K/V) + Round 7
// outproj (LDS-staged MFMA) restored. R8's zero-LDS outproj regressed ~12us:
// per-lane row-major B-frag loads touch 16 scattered cache lines per
// instruction (16x VMEM txn amplification) and re-read Wp 128 MB vs 32 MB.

constexpr int cD  = 256;
constexpr int cL  = 1024;
constexpr int cH  = 8;
constexpr int cDK = 32;

typedef _Float16 f16;
typedef __attribute__((ext_vector_type(8))) _Float16 h8;   // 8 f16 = 4 VGPRs
typedef __attribute__((ext_vector_type(4))) _Float16 h4;   // 8 B
typedef __attribute__((ext_vector_type(4))) float f4v;     // MFMA C/D

// ---------------------------------------------------------------------------
// Kernel 1: Q,K,V projections via MFMA, zero LDS. grid 1024 = lt*64 + bh;
// wave w owns l-subtile l0 + w*16 + ln15.
// D[c][l] = sum_j W[c][j] * X[j][l]  (A = W fp16 frag, B = X^T column frag)
// Outputs: qp[bh][r][c] (B-frag layout for attn), kp[bh][e][c] masked,
// vp[bh][c][e].
// ---------------------------------------------------------------------------
__global__ __launch_bounds__(256, 4) void proj_qkv_kernel(
    const float* __restrict__ queries, const float* __restrict__ keys,
    const float* __restrict__ values, const float* __restrict__ mask,
    const float* __restrict__ Wq, const float* __restrict__ Wk,
    const float* __restrict__ Wv, f16* __restrict__ qp_h,
    f16* __restrict__ kp_h, f16* __restrict__ vp_h)
{
    const int t    = threadIdx.x;
    const int bid  = blockIdx.x;
    const int bh   = bid & 63;             // XCD = bh%8, matches attn
    const int lt   = bid >> 6;
    const int h    = bh & 7;
    const int b    = bh >> 3;
    const int l0   = lt * 64;
    const int lane = t & 63, w = t >> 6, ln15 = lane & 15, lq = lane >> 4;
    const int l    = l0 + w * 16 + ln15;     // this lane's l (MFMA n-index)

    const float mk = mask[b * cL + l];
    const size_t xbase = ((size_t)(b * cD + h * cDK)) * cL + l;   // + j*cL
    const int    wbase = h * cDK * cDK + lq * 8;                  // + c*cDK

    const float* Xs[3] = {queries, keys, values};
    const float* Ws[3] = {Wq, Wk, Wv};
    f4v d0[3], d1[3];

    #pragma unroll
    for (int m = 0; m < 3; ++m) {
        const float* __restrict__ X = Xs[m];
        const float* __restrict__ W = Ws[m];
        h8 bx, a0, a1;
        #pragma unroll
        for (int i = 0; i < 8; ++i)
            bx[i] = (f16)X[xbase + (size_t)(lq * 8 + i) * cL];
        #pragma unroll
        for (int i = 0; i < 8; ++i) {
            a0[i] = (f16)W[wbase + ln15 * cDK + i];
            a1[i] = (f16)W[wbase + (16 + ln15) * cDK + i];
        }
        f4v z = {0.f, 0.f, 0.f, 0.f};
        d0[m] = __builtin_amdgcn_mfma_f32_16x16x32_f16(a0, bx, z, 0, 0, 0);
        d1[m] = __builtin_amdgcn_mfma_f32_16x16x32_f16(a1, bx, z, 0, 0, 0);
    }

    // ---- Q: [r=l][c], fp16 ----
    {
        const size_t qb = ((size_t)bh * cL + l) * cDK;
        h4 o0, o1;
        #pragma unroll
        for (int i = 0; i < 4; ++i) { o0[i] = (f16)d0[0][i]; o1[i] = (f16)d1[0][i]; }
        *reinterpret_cast<h4*>(&qp_h[qb + lq * 4])      = o0;
        *reinterpret_cast<h4*>(&qp_h[qb + 16 + lq * 4]) = o1;
    }
    // ---- K: [e=l][c], masked ----
    {
        const size_t kb = ((size_t)bh * cL + l) * cDK;
        h4 o0, o1;
        #pragma unroll
        for (int i = 0; i < 4; ++i) {
            o0[i] = (f16)(d0[1][i] * mk);
            o1[i] = (f16)(d1[1][i] * mk);
        }
        *reinterpret_cast<h4*>(&kp_h[kb + lq * 4])      = o0;
        *reinterpret_cast<h4*>(&kp_h[kb + 16 + lq * 4]) = o1;
    }
    // ---- V: [c][e=l] ----
    {
        const size_t vb = (size_t)bh * cDK * cL + l;
        #pragma unroll
        for (int i = 0; i < 4; ++i) {
            vp_h[vb + (size_t)(lq * 4 + i) * cL]      = (f16)d0[2][i];
            vp_h[vb + (size_t)(16 + lq * 4 + i) * cL] = (f16)d1[2][i];
        }
    }
}

// ---------------------------------------------------------------------------
// Kernel 2: fused attention, fp16 MFMA. Block = (b, h, 64-row strip), 4
// waves; wave w owns rows r = w*16 + ln15 (one row per lane end-to-end).
// grid 1024 = strip*64 + bh: XCD = bh%8 for every strip -> each XCD's L2
// serves its 8 bh's K/V (1 MB) for all 16 strips. 28 KB LDS -> 5 blocks/CU.
// ---------------------------------------------------------------------------
__global__ __launch_bounds__(256, 5) void attn_kernel(
    const float* __restrict__ mask, const f16* __restrict__ qp_h,
    const f16* __restrict__ kp_h, const f16* __restrict__ vp_h,
    f16* __restrict__ val_h)
{
    __shared__ __align__(16) char smem[28672];
    f16* ks  = (f16*)smem;             // [2][64e][40]  10240 B, rows 80 B
    f16* vsb = (f16*)(smem + 10240);   // [2][32c][72]   9216 B, rows 144 B
    f16* pbf = (f16*)(smem + 19456);   // [64r][72]      9216 B, rows 144 B

    const int t     = threadIdx.x;
    const int bid   = blockIdx.x;
    const int bh    = bid & 63;        // XCD = bh%8: strip-invariant
    const int strip = bid >> 6;
    const int b     = bh >> 3;
    const int r0    = strip * 64;
    const int lane  = t & 63;
    const int w     = t >> 6;
    const int ln15  = lane & 15;
    const int lq    = lane >> 4;

    const size_t kvbase = ((size_t)bh) * 32768;             // f16 units
    const int se = t >> 2, sb = (t & 3) * 8;                // K staging coords
    const int vc = t >> 3, veb = (t & 7) * 8;               // V staging coords

    // ---- persistent B-frag: this lane's q row, straight from global ----
    const h8 qf = *reinterpret_cast<const h8*>(
        &qp_h[((size_t)bh * cL + r0 + w * 16 + ln15) * cDK + lq * 8]);

    // ---- stage tile 0 into buf 0 ----
    {
        h8 kh = *reinterpret_cast<const h8*>(&kp_h[kvbase + se * 32 + sb]);
        *reinterpret_cast<h8*>(&ks[se * 40 + sb]) = kh;
        h8 vv = *reinterpret_cast<const h8*>(&vp_h[kvbase + vc * 1024 + veb]);
        *reinterpret_cast<h8*>(&vsb[vc * 72 + veb]) = vv;
    }

    f4v o0 = {0.f, 0.f, 0.f, 0.f}, o1 = {0.f, 0.f, 0.f, 0.f};
    float mo = -INFINITY, lrp = 0.f;   // lrp: per-lane partial (16 e-cols)
    const int prow  = (w * 16 + ln15) * 72;
    const int vsoff = ln15 * 72 + lq * 8;

    for (int et = 0; et < 16; ++et) {
        __syncthreads();        // tile et visible in buf pp
        const int pp = et & 1;
        const bool pre = (et < 15);
        h8 khp, vvp;
        if (pre) {              // early global loads for tile et+1
            const int e0n = (et + 1) * 64;
            khp = *reinterpret_cast<const h8*>(&kp_h[kvbase + (e0n + se) * 32 + sb]);
            vvp = *reinterpret_cast<const h8*>(&vp_h[kvbase + vc * 1024 + e0n + veb]);
        }
        // mask for this tile: broadcast global reads (L1-hot), prefetched
        float4 mk4[4];
        #pragma unroll
        for (int es = 0; es < 4; ++es)
            mk4[es] = *reinterpret_cast<const float4*>(
                &mask[b * cL + et * 64 + es * 16 + lq * 4]);

        // ---- S^T tiles: D[e][r] = K[e][c] x Q^T[c][r] ----
        f4v sA[4];
        #pragma unroll
        for (int es = 0; es < 4; ++es) {
            const h8 kf = *reinterpret_cast<const h8*>(
                &ks[pp * 2560 + (es * 16 + ln15) * 40 + lq * 8]);
            f4v z = {0.f, 0.f, 0.f, 0.f};
            sA[es] = __builtin_amdgcn_mfma_f32_16x16x32_f16(kf, qf, z, 0, 0, 0);
        }

        // ---- softmax: lane owns row r = w*16+ln15 (scalar stats) ----
        float tm = fmaxf(fmaxf(fmaxf(sA[0][0], sA[0][1]), fmaxf(sA[0][2], sA[0][3])),
                   fmaxf(fmaxf(fmaxf(sA[1][0], sA[1][1]), fmaxf(sA[1][2], sA[1][3])),
                   fmaxf(fmaxf(fmaxf(sA[2][0], sA[2][1]), fmaxf(sA[2][2], sA[2][3])),
                         fmaxf(fmaxf(sA[3][0], sA[3][1]), fmaxf(sA[3][2], sA[3][3])))));
        tm = fmaxf(tm, __shfl_xor(tm, 16));
        tm = fmaxf(tm, __shfl_xor(tm, 32));
        const float mn = fmaxf(mo, tm);
        const float al = __expf(mo - mn);     // first tile: exp(-inf) = 0
        mo = mn;
        o0[0] *= al; o0[1] *= al; o0[2] *= al; o0[3] *= al;
        o1[0] *= al; o1[1] *= al; o1[2] *= al; o1[3] *= al;

        float ps = 0.f;
        #pragma unroll
        for (int es = 0; es < 4; ++es) {
            // p = mask * exp(s - mn): inner mask-mul redundant (masked s=0<=mn)
            float p0 = mk4[es].x * __expf(sA[es][0] - mn);
            float p1 = mk4[es].y * __expf(sA[es][1] - mn);
            float p2 = mk4[es].z * __expf(sA[es][2] - mn);
            float p3 = mk4[es].w * __expf(sA[es][3] - mn);
            ps += (p0 + p1) + (p2 + p3);
            h4 pk; pk[0] = (f16)p0; pk[1] = (f16)p1; pk[2] = (f16)p2; pk[3] = (f16)p3;
            *reinterpret_cast<h4*>(&pbf[prow + es * 16 + lq * 4]) = pk;  // wave-private
        }
        lrp = lrp * al + ps;   // shuffle-reduce deferred to epilogue

        // ---- PV: o^T[c][r] += V[c][e] x P^T[e][r] (same-wave, no barrier) ----
        #pragma unroll
        for (int ch = 0; ch < 2; ++ch) {
            h8 pf  = *reinterpret_cast<const h8*>(&pbf[prow + ch * 32 + lq * 8]);
            h8 va0 = *reinterpret_cast<const h8*>(&vsb[pp * 2304 + vsoff + ch * 32]);
            h8 va1 = *reinterpret_cast<const h8*>(&vsb[pp * 2304 + vsoff + ch * 32 + 1152]);
            o0 = __builtin_amdgcn_mfma_f32_16x16x32_f16(va0, pf, o0, 0, 0, 0);
            o1 = __builtin_amdgcn_mfma_f32_16x16x32_f16(va1, pf, o1, 0, 0, 0);
        }

        // ---- late LDS writes: publish tile et+1 into buf pp^1 ----
        if (pre) {
            *reinterpret_cast<h8*>(&ks[(pp ^ 1) * 2560 + se * 40 + sb]) = khp;
            *reinterpret_cast<h8*>(&vsb[(pp ^ 1) * 2304 + vc * 72 + veb]) = vvp;
        }
    }

    // ---- epilogue: complete row-sum, divide, store ----
    {
        float lr = lrp;
        lr += __shfl_xor(lr, 16);
        lr += __shfl_xor(lr, 32);
        const float linv = 1.0f / (lr + 1e-8f);
        const int h = bh & 7;
        const size_t obase = ((size_t)(b * cL + r0 + w * 16 + ln15)) * cD + h * cDK;
        h4 q0, q1;
        #pragma unroll
        for (int i = 0; i < 4; ++i) {
            q0[i] = (f16)(o0[i] * linv);
            q1[i] = (f16)(o1[i] * linv);
        }
        *reinterpret_cast<h4*>(&val_h[obase + lq * 4])      = q0;
        *reinterpret_cast<h4*>(&val_h[obase + 16 + lq * 4]) = q1;
    }
}

// ---------------------------------------------------------------------------
// Kernel 3: out[b][l][i] = mask[b][l] * (sum_j Wp[i][j]*val[b][l][j] + bp[i])
// fp16 MFMA, LDS-staged (R7 version). grid 512 = (b:8, lt:16 of 64 l,
// it:4 of 64 i), block 256.
// ---------------------------------------------------------------------------
__global__ __launch_bounds__(256, 2) void outproj_kernel(
    const f16* __restrict__ val_h, const float* __restrict__ Wp,
    const float* __restrict__ bp, const float* __restrict__ mask,
    float* __restrict__ out)
{
    __shared__ __align__(16) f16 vt[64 * 264];    // [64 l][264 j-pad] rows 528 B
    __shared__ __align__(16) f16 wpb[64 * 264];   // [64 i][264 j-pad]
    __shared__ float mrow[64];

    const int t    = threadIdx.x;
    const int bid  = blockIdx.x;
    const int it   = bid & 3;
    const int lt   = (bid >> 2) & 15;
    const int b    = bid >> 6;
    const int l0   = lt * 64, i0 = it * 64;
    const int lane = t & 63, w = t >> 6, ln15 = lane & 15, lq = lane >> 4;

    {   // stage val tile; row = t&63 fast -> conflict-free LDS writes
        int row = t & 63, seg = (t >> 6) * 64;
        const f16* src = &val_h[((size_t)(b * cL + l0 + row)) * cD + seg];
        #pragma unroll
        for (int k = 0; k < 8; ++k)
            *reinterpret_cast<h8*>(&vt[row * 264 + seg + k * 8]) =
                *reinterpret_cast<const h8*>(src + k * 8);
    }
    {   // stage Wp tile (fp32 -> fp16)
        int row = t & 63, seg = (t >> 6) * 64;
        const float* src = &Wp[((size_t)(i0 + row)) * cD + seg];
        #pragma unroll
        for (int k = 0; k < 8; ++k) {
            float4 f0 = *reinterpret_cast<const float4*>(src + k * 8);
            float4 f1 = *reinterpret_cast<const float4*>(src + k * 8 + 4);
            h8 hv;
            hv[0] = (f16)f0.x; hv[1] = (f16)f0.y; hv[2] = (f16)f0.z; hv[3] = (f16)f0.w;
            hv[4] = (f16)f1.x; hv[5] = (f16)f1.y; hv[6] = (f16)f1.z; hv[7] = (f16)f1.w;
            *reinterpret_cast<h8*>(&wpb[row * 264 + seg + k * 8]) = hv;
        }
    }
    if (t < 64) mrow[t] = mask[b * cL + l0 + t];
    __syncthreads();

    f4v acc[4] = {{0.f, 0.f, 0.f, 0.f}, {0.f, 0.f, 0.f, 0.f},
                  {0.f, 0.f, 0.f, 0.f}, {0.f, 0.f, 0.f, 0.f}};
    #pragma unroll
    for (int kc = 0; kc < 8; ++kc) {
        h8 aA = *reinterpret_cast<const h8*>(&vt[(w * 16 + ln15) * 264 + kc * 32 + lq * 8]);
        #pragma unroll
        for (int ti = 0; ti < 4; ++ti) {
            h8 bB = *reinterpret_cast<const h8*>(&wpb[(ti * 16 + ln15) * 264 + kc * 32 + lq * 8]);
            acc[ti] = __builtin_amdgcn_mfma_f32_16x16x32_f16(aA, bB, acc[ti], 0, 0, 0);
        }
    }

    float mk[4];
    #pragma unroll
    for (int rg = 0; rg < 4; ++rg) mk[rg] = mrow[w * 16 + lq * 4 + rg];
    #pragma unroll
    for (int ti = 0; ti < 4; ++ti) {
        float bpv = bp[i0 + ti * 16 + ln15];
        #pragma unroll
        for (int rg = 0; rg < 4; ++rg) {
            int l = l0 + w * 16 + lq * 4 + rg;
            out[((size_t)(b * cL + l)) * cD + i0 + ti * 16 + ln15] =
                (acc[ti][rg] + bpv) * mk[rg];
        }
    }
}

// ---------------------------------------------------------------------------
extern "C" void kernel_launch(void* const* d_in, const int* in_sizes, int n_in,
                              void* d_out, int out_size, void* d_ws, size_t ws_size,
                              hipStream_t stream) {
    const float* queries = (const float*)d_in[0];
    const float* keys    = (const float*)d_in[1];
    const float* values  = (const float*)d_in[2];
    const float* mask    = (const float*)d_in[3];
    const float* Wq      = (const float*)d_in[4];
    const float* Wk      = (const float*)d_in[5];
    const float* Wv      = (const float*)d_in[6];
    const float* Wp      = (const float*)d_in[7];
    const float* bp      = (const float*)d_in[8];
    float* out = (float*)d_out;

    // ws: qp 4MB | kp 4MB | vp 4MB | val 4MB  (16 MB)
    char* wsb = (char*)d_ws;
    f16* qp_h  = (f16*)(wsb);
    f16* kp_h  = (f16*)(wsb + (4u << 20));
    f16* vp_h  = (f16*)(wsb + (8u << 20));
    f16* val_h = (f16*)(wsb + (12u << 20));

    proj_qkv_kernel<<<dim3(1024), dim3(256), 0, stream>>>(
        queries, keys, values, mask, Wq, Wk, Wv, qp_h, kp_h, vp_h);
    attn_kernel<<<dim3(1024), dim3(256), 0, stream>>>(
        mask, qp_h, kp_h, vp_h, val_h);
    outproj_kernel<<<dim3(512), dim3(256), 0, stream>>>(val_h, Wp, bp, mask, out);
}